// Round 1
// baseline (9544.680 us; speedup 1.0000x reference)
//
#include <hip/hip_runtime.h>
#include <math.h>

// Problem sizes
#define BB 64    // batch
#define SS 128   // src seq len
#define TD 63    // decoder steps (T_TRG-1)
#define EE 512   // embed dim
#define HH 1024  // hidden
#define G4 4096  // 4*H

// ---------------- kernels ----------------

__global__ __launch_bounds__(256) void zero_kernel(float* __restrict__ p, int n) {
  int i = blockIdx.x * 256 + threadIdx.x;
  if (i < n) p[i] = 0.f;
}

// out[b][0][:] = 0 ; grid 64 blocks, 512 threads
__global__ __launch_bounds__(512) void zero_row0(float* __restrict__ out) {
  out[(size_t)blockIdx.x * 64 * 512 + threadIdx.x] = 0.f;
}

// dst[s][b][e] (time-major), grid = 128*64, 128 thr * float4
__global__ __launch_bounds__(128) void embed_src(const int* __restrict__ src,
                                                 const float* __restrict__ tab,
                                                 float* __restrict__ dst) {
  int s = blockIdx.x >> 6;
  int b = blockIdx.x & 63;
  int tok = src[b * SS + s];
  const float4* row = reinterpret_cast<const float4*>(tab + (size_t)tok * EE);
  float4* o = reinterpret_cast<float4*>(dst + ((size_t)s * BB + b) * EE);
  o[threadIdx.x] = row[threadIdx.x];
}

// dec_tokens[b][t] = (t==0) ? SOS(=1) : trg[b][t];  dst[t][b][e], grid 63*64
__global__ __launch_bounds__(128) void embed_dec(const int* __restrict__ trg,
                                                 const float* __restrict__ tab,
                                                 float* __restrict__ dst) {
  int t = blockIdx.x >> 6;
  int b = blockIdx.x & 63;
  int tok = (t == 0) ? 1 : trg[b * 64 + t];
  const float4* row = reinterpret_cast<const float4*>(tab + (size_t)tok * EE);
  float4* o = reinterpret_cast<float4*>(dst + ((size_t)t * BB + b) * EE);
  o[threadIdx.x] = row[threadIdx.x];
}

// C[M,N] = A[M,K] @ W[N,K]^T + b0 + b1.  Tiles 64x64, BK=16, 256 thr, 4x4/thread.
// grid = (M/64, N/64). M,N,K all multiples of 64/64/16 in this problem.
__global__ __launch_bounds__(256) void gemm_bias(const float* __restrict__ A,
                                                 const float* __restrict__ W,
                                                 const float* __restrict__ b0,
                                                 const float* __restrict__ b1,
                                                 float* __restrict__ C,
                                                 int N, int K) {
  __shared__ float As[16][64];
  __shared__ float Ws[16][64];
  const int tid = threadIdx.x;
  const int m0 = blockIdx.x << 6;
  const int n0 = blockIdx.y << 6;
  const int lr = tid >> 2;
  const int lk = (tid & 3) << 2;
  const int tm = (tid >> 4) << 2;
  const int tn = (tid & 15) << 2;
  float acc[4][4] = {};
  for (int k0 = 0; k0 < K; k0 += 16) {
    float4 a4 = *reinterpret_cast<const float4*>(A + (size_t)(m0 + lr) * K + k0 + lk);
    float4 w4 = *reinterpret_cast<const float4*>(W + (size_t)(n0 + lr) * K + k0 + lk);
    __syncthreads();
    As[lk + 0][lr] = a4.x; As[lk + 1][lr] = a4.y; As[lk + 2][lr] = a4.z; As[lk + 3][lr] = a4.w;
    Ws[lk + 0][lr] = w4.x; Ws[lk + 1][lr] = w4.y; Ws[lk + 2][lr] = w4.z; Ws[lk + 3][lr] = w4.w;
    __syncthreads();
#pragma unroll
    for (int kk = 0; kk < 16; ++kk) {
      float4 av = *reinterpret_cast<const float4*>(&As[kk][tm]);
      float4 wv = *reinterpret_cast<const float4*>(&Ws[kk][tn]);
      float a_[4] = {av.x, av.y, av.z, av.w};
      float w_[4] = {wv.x, wv.y, wv.z, wv.w};
#pragma unroll
      for (int i = 0; i < 4; ++i)
#pragma unroll
        for (int j = 0; j < 4; ++j) acc[i][j] = fmaf(a_[i], w_[j], acc[i][j]);
    }
  }
  float bias[4];
#pragma unroll
  for (int j = 0; j < 4; ++j) {
    float v = 0.f;
    if (b0) v += b0[n0 + tn + j];
    if (b1) v += b1[n0 + tn + j];
    bias[j] = v;
  }
#pragma unroll
  for (int i = 0; i < 4; ++i) {
    float4 o;
    o.x = acc[i][0] + bias[0];
    o.y = acc[i][1] + bias[1];
    o.z = acc[i][2] + bias[2];
    o.w = acc[i][3] + bias[3];
    *reinterpret_cast<float4*>(C + (size_t)(m0 + tm + i) * N + n0 + tn) = o;
  }
}

// partial[ks][b][n] = sum_{k in ks-th 256-chunk} h[b][k]*Whh[n][k]
// grid = (64 n-tiles, 4 k-splits), 256 thr, tile 64x64.
__global__ __launch_bounds__(256) void gemm_rec(const float* __restrict__ hS,
                                                const float* __restrict__ Whh,
                                                float* __restrict__ partial) {
  __shared__ float As[16][64];
  __shared__ float Ws[16][64];
  const int tid = threadIdx.x;
  const int n0 = blockIdx.x << 6;
  const int ks = blockIdx.y;
  const int kb = ks << 8;
  const int lr = tid >> 2;
  const int lk = (tid & 3) << 2;
  const int tm = (tid >> 4) << 2;
  const int tn = (tid & 15) << 2;
  float acc[4][4] = {};
  for (int k0 = 0; k0 < 256; k0 += 16) {
    float4 a4 = *reinterpret_cast<const float4*>(hS + (size_t)lr * HH + kb + k0 + lk);
    float4 w4 = *reinterpret_cast<const float4*>(Whh + (size_t)(n0 + lr) * HH + kb + k0 + lk);
    __syncthreads();
    As[lk + 0][lr] = a4.x; As[lk + 1][lr] = a4.y; As[lk + 2][lr] = a4.z; As[lk + 3][lr] = a4.w;
    Ws[lk + 0][lr] = w4.x; Ws[lk + 1][lr] = w4.y; Ws[lk + 2][lr] = w4.z; Ws[lk + 3][lr] = w4.w;
    __syncthreads();
#pragma unroll
    for (int kk = 0; kk < 16; ++kk) {
      float4 av = *reinterpret_cast<const float4*>(&As[kk][tm]);
      float4 wv = *reinterpret_cast<const float4*>(&Ws[kk][tn]);
      float a_[4] = {av.x, av.y, av.z, av.w};
      float w_[4] = {wv.x, wv.y, wv.z, wv.w};
#pragma unroll
      for (int i = 0; i < 4; ++i)
#pragma unroll
        for (int j = 0; j < 4; ++j) acc[i][j] = fmaf(a_[i], w_[j], acc[i][j]);
    }
  }
#pragma unroll
  for (int i = 0; i < 4; ++i) {
    float4 o = {acc[i][0], acc[i][1], acc[i][2], acc[i][3]};
    *reinterpret_cast<float4*>(partial + ((size_t)ks * BB + tm + i) * G4 + n0 + tn) = o;
  }
}

// gates = Gpre(t) + sum_ks partial ; LSTM cell update. grid 256 x 256 thr.
__global__ __launch_bounds__(256) void lstm_point(const float* __restrict__ Gpre,
                                                  const float* __restrict__ partial,
                                                  float* __restrict__ hS,
                                                  float* __restrict__ cS,
                                                  float* __restrict__ outSeq) {
  int idx = blockIdx.x * 256 + threadIdx.x;  // b*1024 + j
  int b = idx >> 10;
  int j = idx & 1023;
  const float* g = Gpre + (size_t)b * G4;
  float gi = g[j], gf = g[j + 1024], gg = g[j + 2048], go = g[j + 3072];
#pragma unroll
  for (int ks = 0; ks < 4; ++ks) {
    const float* p = partial + ((size_t)ks * BB + b) * G4;
    gi += p[j]; gf += p[j + 1024]; gg += p[j + 2048]; go += p[j + 3072];
  }
  float c = cS[idx];
  float ii = 1.f / (1.f + expf(-gi));
  float ff = 1.f / (1.f + expf(-gf));
  float oo = 1.f / (1.f + expf(-go));
  float cn = ff * c + ii * tanhf(gg);
  float hn = oo * tanhf(cn);
  cS[idx] = cn;
  hS[idx] = hn;
  if (outSeq) outSeq[idx] = hn;
}

// scores[t][b][s] = dot(preds[t][b], srcEmb[s][b]) / sqrt(512). grid (64 b, 8 t-tiles)
__global__ __launch_bounds__(256) void attn_scores(const float* __restrict__ preds,
                                                   const float* __restrict__ srcEmb,
                                                   float* __restrict__ scores) {
  __shared__ float P[8][516];  // +4 pad: breaks 8-way bank conflict on P[tl][k]
  const int b = blockIdx.x;
  const int t0 = blockIdx.y << 3;
  const int nt = (TD - t0 < 8) ? (TD - t0) : 8;
  for (int i = threadIdx.x; i < nt * 512; i += 256) {
    int tl = i >> 9, k = i & 511;
    P[tl][k] = preds[((size_t)(t0 + tl) * BB + b) * EE + k];
  }
  __syncthreads();
  const int s = threadIdx.x & 127;
  const int half = threadIdx.x >> 7;
  const float* se = srcEmb + ((size_t)s * BB + b) * EE;
  float acc[4] = {};
  for (int k = 0; k < 512; ++k) {
    float v = se[k];
#pragma unroll
    for (int i = 0; i < 4; ++i) acc[i] = fmaf(v, P[(half << 2) + i][k], acc[i]);
  }
  const float inv = 0.04419417382415922f;  // 1/sqrt(512)
#pragma unroll
  for (int i = 0; i < 4; ++i) {
    int tl = (half << 2) + i;
    if (tl < nt) scores[((size_t)(t0 + tl) * BB + b) * 128 + s] = acc[i] * inv;
  }
}

// softmax over s (128) per (t,b) row; one wave per row; write attn weights for t==62.
__global__ __launch_bounds__(256) void softmax_attn(float* __restrict__ scores,
                                                    float* __restrict__ attnOut) {
  int row = blockIdx.x * 4 + (threadIdx.x >> 6);  // row = t*64 + b
  int lane = threadIdx.x & 63;
  float* r = scores + (size_t)row * 128;
  float v0 = r[lane], v1 = r[lane + 64];
  float m = fmaxf(v0, v1);
#pragma unroll
  for (int off = 32; off; off >>= 1) m = fmaxf(m, __shfl_xor(m, off));
  float e0 = expf(v0 - m), e1 = expf(v1 - m);
  float ssum = e0 + e1;
#pragma unroll
  for (int off = 32; off; off >>= 1) ssum += __shfl_xor(ssum, off);
  float inv = 1.f / ssum;
  e0 *= inv; e1 *= inv;
  r[lane] = e0; r[lane + 64] = e1;
  if ((row >> 6) == 62) {  // last decoder step
    int b = row & 63;
    attnOut[b * 128 + lane] = e0;
    attnOut[b * 128 + lane + 64] = e1;
  }
}

// out[b][t+1][e] = sum_s attn[t][b][s] * srcEmb[s][b][e]. grid (64 b, 8 t-tiles)
__global__ __launch_bounds__(256) void attn_ctx(const float* __restrict__ attn,
                                                const float* __restrict__ srcEmb,
                                                float* __restrict__ out) {
  __shared__ float Wt[8][128];
  const int b = blockIdx.x;
  const int t0 = blockIdx.y << 3;
  const int nt = (TD - t0 < 8) ? (TD - t0) : 8;
  for (int i = threadIdx.x; i < nt * 128; i += 256) {
    int tl = i >> 7, s = i & 127;
    Wt[tl][s] = attn[((size_t)(t0 + tl) * BB + b) * 128 + s];
  }
  __syncthreads();
  const int e = threadIdx.x << 1;
  float acc[8][2] = {};
  for (int s = 0; s < 128; ++s) {
    float2 v = *reinterpret_cast<const float2*>(srcEmb + ((size_t)s * BB + b) * EE + e);
#pragma unroll
    for (int tl = 0; tl < 8; ++tl) {
      acc[tl][0] = fmaf(Wt[tl][s], v.x, acc[tl][0]);
      acc[tl][1] = fmaf(Wt[tl][s], v.y, acc[tl][1]);
    }
  }
  for (int tl = 0; tl < nt; ++tl) {
    float2 o = {acc[tl][0], acc[tl][1]};
    *reinterpret_cast<float2*>(out + ((size_t)b * 64 + (t0 + tl + 1)) * EE + e) = o;
  }
}

// ---------------- host ----------------

extern "C" void kernel_launch(void* const* d_in, const int* in_sizes, int n_in,
                              void* d_out, int out_size, void* d_ws, size_t ws_size,
                              hipStream_t stream) {
  const int* src = (const int*)d_in[0];
  const int* trg = (const int*)d_in[1];
  const float* srcTab = (const float*)d_in[2];
  const float* trgTab = (const float*)d_in[3];
  const float* fcW = (const float*)d_in[4];
  const float* fcB = (const float*)d_in[5];
  // layer index: 0=enc0, 1=enc1, 2=dec0, 3=dec1
  const float* Wih[4] = {(const float*)d_in[6], (const float*)d_in[10], (const float*)d_in[14], (const float*)d_in[18]};
  const float* Whh[4] = {(const float*)d_in[7], (const float*)d_in[11], (const float*)d_in[15], (const float*)d_in[19]};
  const float* bih[4] = {(const float*)d_in[8], (const float*)d_in[12], (const float*)d_in[16], (const float*)d_in[20]};
  const float* bhh[4] = {(const float*)d_in[9], (const float*)d_in[13], (const float*)d_in[17], (const float*)d_in[21]};

  // workspace layout (floats). Total 20,152,320 floats = 80.6 MB, with aliasing:
  //  bufA: encoder-L0 output, later reused as decL0 out + decOut
  //  Gpre: per-chunk input projections, later reused as preds
  //  partial: split-K partials, later reused as scores
  float* ws = (float*)d_ws;
  float* srcEmb  = ws;                   // [128][64][512]  = 4,194,304
  float* bufA    = srcEmb + 4194304;     // 8,388,608
  float* decEmb  = bufA + 8388608;       // [63][64][512]   = 2,064,384
  float* Gpre    = decEmb + 2064384;     // [16][64][4096]  = 4,194,304
  float* partial = Gpre + 4194304;       // [4][64][4096]   = 1,048,576
  float* hS      = partial + 1048576;    // [2][64][1024]   = 131,072
  float* cS      = hS + 131072;          // [2][64][1024]   = 131,072

  float* encL0  = bufA;                  // [128][64][1024]
  float* decL0  = bufA;                  // [63][64][1024] (after encoder done)
  float* decOut = bufA + 4128768;        // [63][64][1024]
  float* preds  = Gpre;                  // [63][64][512]
  float* scores = partial;               // [63][64][128]
  float* out = (float*)d_out;

  embed_src<<<SS * BB, 128, 0, stream>>>(src, srcTab, srcEmb);
  embed_dec<<<TD * BB, 128, 0, stream>>>(trg, trgTab, decEmb);
  zero_kernel<<<262144 / 256, 256, 0, stream>>>(hS, 262144);  // h and c, both layers

  auto run_layer = [&](const float* inSeq, int T, int Din, int li,
                       float* hSt, float* cSt, float* outSeq) {
    for (int t0 = 0; t0 < T; t0 += 16) {
      int ct = (T - t0 < 16) ? (T - t0) : 16;
      // Gpre[tc][b][:] = x @ Wih^T + bih + bhh for the chunk
      gemm_bias<<<dim3(ct, G4 / 64), 256, 0, stream>>>(
          inSeq + (size_t)t0 * BB * Din, Wih[li], bih[li], bhh[li], Gpre, G4, Din);
      for (int tc = 0; tc < ct; ++tc) {
        gemm_rec<<<dim3(64, 4), 256, 0, stream>>>(hSt, Whh[li], partial);
        lstm_point<<<256, 256, 0, stream>>>(
            Gpre + (size_t)tc * BB * G4, partial, hSt, cSt,
            outSeq ? outSeq + (size_t)(t0 + tc) * BB * HH : (float*)nullptr);
      }
    }
  };

  run_layer(srcEmb, SS, EE, 0, hS, cS, encL0);
  run_layer(encL0, SS, HH, 1, hS + 65536, cS + 65536, nullptr);  // only final h,c needed
  run_layer(decEmb, TD, EE, 2, hS, cS, decL0);                   // states continue from encoder
  run_layer(decL0, TD, HH, 3, hS + 65536, cS + 65536, decOut);

  // preds = decOut @ fcW^T + fcB   [4032, 512]
  gemm_bias<<<dim3(4032 / 64, 512 / 64), 256, 0, stream>>>(decOut, fcW, fcB, nullptr, preds, 512, 1024);
  attn_scores<<<dim3(64, 8), 256, 0, stream>>>(preds, srcEmb, scores);
  softmax_attn<<<1008, 256, 0, stream>>>(scores, out + 2097152);
  attn_ctx<<<dim3(64, 8), 256, 0, stream>>>(scores, srcEmb, out);
  zero_row0<<<64, 512, 0, stream>>>(out);
}

// Round 3
// 6896.506 us; speedup vs baseline: 1.3840x; 1.3840x over previous
//
#include <hip/hip_runtime.h>
#include <math.h>

#define BB 64    // batch
#define SS 128   // src seq len
#define TD 63    // decoder steps
#define EE 512   // embed dim
#define HH 1024  // hidden
#define G4 4096  // 4*H

typedef __attribute__((ext_vector_type(8))) short bf16x8;
typedef __attribute__((ext_vector_type(4))) float f32x4;

// split fp32 -> bf16 hi + bf16 lo (x ~= hi + lo), RNE both
__device__ inline void bf16split(float x, short& hi, short& lo) {
  unsigned u = __float_as_uint(x);
  unsigned uh = (u + 0x7FFFu + ((u >> 16) & 1u)) & 0xFFFF0000u;
  hi = (short)(uh >> 16);
  float r = x - __uint_as_float(uh);
  unsigned v = __float_as_uint(r);
  unsigned vh = (v + 0x7FFFu + ((v >> 16) & 1u)) & 0xFFFF0000u;
  lo = (short)(vh >> 16);
}

// convert 8 consecutive floats -> two b128 LDS stores (hi, lo)
__device__ inline void stage8(const float* __restrict__ src, short* dh, short* dl) {
  float4 f0 = *(const float4*)(src);
  float4 f1 = *(const float4*)(src + 4);
  bf16x8 vh, vl; short h, l;
  bf16split(f0.x, h, l); vh[0] = h; vl[0] = l;
  bf16split(f0.y, h, l); vh[1] = h; vl[1] = l;
  bf16split(f0.z, h, l); vh[2] = h; vl[2] = l;
  bf16split(f0.w, h, l); vh[3] = h; vl[3] = l;
  bf16split(f1.x, h, l); vh[4] = h; vl[4] = l;
  bf16split(f1.y, h, l); vh[5] = h; vl[5] = l;
  bf16split(f1.z, h, l); vh[6] = h; vl[6] = l;
  bf16split(f1.w, h, l); vh[7] = h; vl[7] = l;
  *(bf16x8*)dh = vh;
  *(bf16x8*)dl = vl;
}

// ---------------- small kernels ----------------

__global__ __launch_bounds__(256) void zero_kernel(float* __restrict__ p, int n) {
  int i = blockIdx.x * 256 + threadIdx.x;
  if (i < n) p[i] = 0.f;
}

__global__ __launch_bounds__(512) void zero_row0(float* __restrict__ out) {
  out[(size_t)blockIdx.x * 64 * 512 + threadIdx.x] = 0.f;
}

__global__ __launch_bounds__(128) void embed_src(const int* __restrict__ src,
                                                 const float* __restrict__ tab,
                                                 float* __restrict__ dst) {
  int s = blockIdx.x >> 6;
  int b = blockIdx.x & 63;
  int tok = src[b * SS + s];
  const float4* row = reinterpret_cast<const float4*>(tab + (size_t)tok * EE);
  float4* o = reinterpret_cast<float4*>(dst + ((size_t)s * BB + b) * EE);
  o[threadIdx.x] = row[threadIdx.x];
}

__global__ __launch_bounds__(128) void embed_dec(const int* __restrict__ trg,
                                                 const float* __restrict__ tab,
                                                 float* __restrict__ dst) {
  int t = blockIdx.x >> 6;
  int b = blockIdx.x & 63;
  int tok = (t == 0) ? 1 : trg[b * 64 + t];
  const float4* row = reinterpret_cast<const float4*>(tab + (size_t)tok * EE);
  float4* o = reinterpret_cast<float4*>(dst + ((size_t)t * BB + b) * EE);
  o[threadIdx.x] = row[threadIdx.x];
}

// ---------------- MFMA projection GEMM ----------------
// C[M,N] = A[M,K] @ W[N,K]^T + b0 + b1, bf16x3. Tile 128x128, BK=32.
// grid (M/128, N/128); M%128==0, N%128==0, K%32==0.
__global__ __launch_bounds__(256) void gemm_proj_mfma(
    const float* __restrict__ A, const float* __restrict__ W,
    const float* __restrict__ b0, const float* __restrict__ b1,
    float* __restrict__ C, int N, int K) {
  __shared__ __align__(16) short Ahi[128 * 40], Alo[128 * 40];
  __shared__ __align__(16) short Bhi[128 * 40], Blo[128 * 40];
  const int tid = threadIdx.x;
  const int m0 = blockIdx.x << 7, n0 = blockIdx.y << 7;
  const int wave = tid >> 6, lane = tid & 63;
  const int wm = wave >> 1, wn = wave & 1;
  const int lr = lane & 15, lk = (lane >> 4) << 3;
  const int srow = tid >> 1, skq = (tid & 1) << 4;
  f32x4 acc[4][4] = {};
  for (int k0 = 0; k0 < K; k0 += 32) {
    __syncthreads();
    stage8(A + (size_t)(m0 + srow) * K + k0 + skq,     Ahi + srow * 40 + skq,     Alo + srow * 40 + skq);
    stage8(A + (size_t)(m0 + srow) * K + k0 + skq + 8, Ahi + srow * 40 + skq + 8, Alo + srow * 40 + skq + 8);
    stage8(W + (size_t)(n0 + srow) * K + k0 + skq,     Bhi + srow * 40 + skq,     Blo + srow * 40 + skq);
    stage8(W + (size_t)(n0 + srow) * K + k0 + skq + 8, Bhi + srow * 40 + skq + 8, Blo + srow * 40 + skq + 8);
    __syncthreads();
    bf16x8 ah[4], al[4], wh[4], wl[4];
#pragma unroll
    for (int mt = 0; mt < 4; ++mt) {
      int r = wm * 64 + mt * 16 + lr;
      ah[mt] = *(bf16x8*)(Ahi + r * 40 + lk);
      al[mt] = *(bf16x8*)(Alo + r * 40 + lk);
    }
#pragma unroll
    for (int ntl = 0; ntl < 4; ++ntl) {
      int r = wn * 64 + ntl * 16 + lr;
      wh[ntl] = *(bf16x8*)(Bhi + r * 40 + lk);
      wl[ntl] = *(bf16x8*)(Blo + r * 40 + lk);
    }
#pragma unroll
    for (int mt = 0; mt < 4; ++mt)
#pragma unroll
      for (int ntl = 0; ntl < 4; ++ntl) {
        acc[mt][ntl] = __builtin_amdgcn_mfma_f32_16x16x32_bf16(ah[mt], wh[ntl], acc[mt][ntl], 0, 0, 0);
        acc[mt][ntl] = __builtin_amdgcn_mfma_f32_16x16x32_bf16(al[mt], wh[ntl], acc[mt][ntl], 0, 0, 0);
        acc[mt][ntl] = __builtin_amdgcn_mfma_f32_16x16x32_bf16(ah[mt], wl[ntl], acc[mt][ntl], 0, 0, 0);
      }
  }
#pragma unroll
  for (int ntl = 0; ntl < 4; ++ntl) {
    int n = n0 + wn * 64 + ntl * 16 + lr;
    float bias = (b0 ? b0[n] : 0.f) + (b1 ? b1[n] : 0.f);
#pragma unroll
    for (int mt = 0; mt < 4; ++mt) {
      int mbase = m0 + wm * 64 + mt * 16 + ((lane >> 4) << 2);
#pragma unroll
      for (int r2 = 0; r2 < 4; ++r2)
        C[(size_t)(mbase + r2) * N + n] = acc[mt][ntl][r2] + bias;
    }
  }
}

// ---------------- MFMA recurrent GEMM ----------------
// partial[ks][b][n] = sum_{k in ks-th 128-chunk} h[b][k] * Whh[n][k], bf16x3.
// grid 256 blocks: nt = blk>>3 (128 n each), ks = blk&7 (128 k each).
__global__ __launch_bounds__(256) void gemm_rec_mfma(
    const float* __restrict__ hS, const float* __restrict__ Whh,
    float* __restrict__ partial) {
  __shared__ __align__(16) short Ahi[64 * 72], Alo[64 * 72];
  __shared__ __align__(16) short Bhi[128 * 72], Blo[128 * 72];
  const int tid = threadIdx.x;
  const int nt = blockIdx.x >> 3, ks = blockIdx.x & 7;
  const int n0 = nt << 7, kb = ks << 7;
  const int wave = tid >> 6, lane = tid & 63;
  const int wm = wave >> 1, wn = wave & 1;
  const int lr = lane & 15, lk = (lane >> 4) << 3;
  const int arow = tid >> 2, akq = (tid & 3) << 4;  // A: 16 floats/thread per ktile
  const int brow = tid >> 1, bkq = (tid & 1) << 5;  // B: 32 floats/thread per ktile
  f32x4 acc[2][4] = {};
  for (int kt = 0; kt < 2; ++kt) {
    const int kbb = kb + kt * 64;
    __syncthreads();
    stage8(hS + (size_t)arow * HH + kbb + akq,     Ahi + arow * 72 + akq,     Alo + arow * 72 + akq);
    stage8(hS + (size_t)arow * HH + kbb + akq + 8, Ahi + arow * 72 + akq + 8, Alo + arow * 72 + akq + 8);
    const float* wsrc = Whh + (size_t)(n0 + brow) * HH + kbb + bkq;
    short* bh = Bhi + brow * 72 + bkq;
    short* bl = Blo + brow * 72 + bkq;
    stage8(wsrc,      bh,      bl);
    stage8(wsrc + 8,  bh + 8,  bl + 8);
    stage8(wsrc + 16, bh + 16, bl + 16);
    stage8(wsrc + 24, bh + 24, bl + 24);
    __syncthreads();
#pragma unroll
    for (int kf = 0; kf < 2; ++kf) {
      const int ko = kf * 32 + lk;
      bf16x8 ah[2], al[2], wh[4], wl[4];
#pragma unroll
      for (int mt = 0; mt < 2; ++mt) {
        int r = (wm * 2 + mt) * 16 + lr;
        ah[mt] = *(bf16x8*)(Ahi + r * 72 + ko);
        al[mt] = *(bf16x8*)(Alo + r * 72 + ko);
      }
#pragma unroll
      for (int ntl = 0; ntl < 4; ++ntl) {
        int r = (wn * 4 + ntl) * 16 + lr;
        wh[ntl] = *(bf16x8*)(Bhi + r * 72 + ko);
        wl[ntl] = *(bf16x8*)(Blo + r * 72 + ko);
      }
#pragma unroll
      for (int mt = 0; mt < 2; ++mt)
#pragma unroll
        for (int ntl = 0; ntl < 4; ++ntl) {
          acc[mt][ntl] = __builtin_amdgcn_mfma_f32_16x16x32_bf16(ah[mt], wh[ntl], acc[mt][ntl], 0, 0, 0);
          acc[mt][ntl] = __builtin_amdgcn_mfma_f32_16x16x32_bf16(al[mt], wh[ntl], acc[mt][ntl], 0, 0, 0);
          acc[mt][ntl] = __builtin_amdgcn_mfma_f32_16x16x32_bf16(ah[mt], wl[ntl], acc[mt][ntl], 0, 0, 0);
        }
    }
  }
#pragma unroll
  for (int mt = 0; mt < 2; ++mt) {
#pragma unroll
    for (int ntl = 0; ntl < 4; ++ntl) {
      int b = wm * 32 + mt * 16 + ((lane >> 4) << 2);
      int n = n0 + wn * 64 + ntl * 16 + lr;
      float* dst = partial + ((size_t)(ks * BB + b)) * G4 + n;
#pragma unroll
      for (int r2 = 0; r2 < 4; ++r2) dst[(size_t)r2 * G4] = acc[mt][ntl][r2];
    }
  }
}

// gates = Gpre(t) + sum_ks partial ; LSTM cell update. grid 256 x 256 thr.
__global__ __launch_bounds__(256) void lstm_point(const float* __restrict__ Gpre,
                                                  const float* __restrict__ partial,
                                                  float* __restrict__ hS,
                                                  float* __restrict__ cS,
                                                  float* __restrict__ outSeq) {
  int idx = blockIdx.x * 256 + threadIdx.x;  // b*1024 + j
  int b = idx >> 10;
  int j = idx & 1023;
  const float* g = Gpre + (size_t)b * G4;
  float gi = g[j], gf = g[j + 1024], gg = g[j + 2048], go = g[j + 3072];
#pragma unroll
  for (int ks = 0; ks < 8; ++ks) {
    const float* p = partial + ((size_t)ks * BB + b) * G4;
    gi += p[j]; gf += p[j + 1024]; gg += p[j + 2048]; go += p[j + 3072];
  }
  float c = cS[idx];
  float ii = 1.f / (1.f + expf(-gi));
  float ff = 1.f / (1.f + expf(-gf));
  float oo = 1.f / (1.f + expf(-go));
  float cn = ff * c + ii * tanhf(gg);
  float hn = oo * tanhf(cn);
  cS[idx] = cn;
  hS[idx] = hn;
  if (outSeq) outSeq[idx] = hn;
}

// ---------------- attention ----------------

__global__ __launch_bounds__(256) void attn_scores(const float* __restrict__ preds,
                                                   const float* __restrict__ srcEmb,
                                                   float* __restrict__ scores) {
  __shared__ float P[8][516];
  const int b = blockIdx.x;
  const int t0 = blockIdx.y << 3;
  const int nt = (TD - t0 < 8) ? (TD - t0) : 8;
  for (int i = threadIdx.x; i < nt * 512; i += 256) {
    int tl = i >> 9, k = i & 511;
    P[tl][k] = preds[((size_t)(t0 + tl) * BB + b) * EE + k];
  }
  __syncthreads();
  const int s = threadIdx.x & 127;
  const int half = threadIdx.x >> 7;
  const float* se = srcEmb + ((size_t)s * BB + b) * EE;
  float acc[4] = {};
  for (int k = 0; k < 512; ++k) {
    float v = se[k];
#pragma unroll
    for (int i = 0; i < 4; ++i) acc[i] = fmaf(v, P[(half << 2) + i][k], acc[i]);
  }
  const float inv = 0.04419417382415922f;  // 1/sqrt(512)
#pragma unroll
  for (int i = 0; i < 4; ++i) {
    int tl = (half << 2) + i;
    if (tl < nt) scores[((size_t)(t0 + tl) * BB + b) * 128 + s] = acc[i] * inv;
  }
}

__global__ __launch_bounds__(256) void softmax_attn(float* __restrict__ scores,
                                                    float* __restrict__ attnOut) {
  int row = blockIdx.x * 4 + (threadIdx.x >> 6);
  int lane = threadIdx.x & 63;
  float* r = scores + (size_t)row * 128;
  float v0 = r[lane], v1 = r[lane + 64];
  float m = fmaxf(v0, v1);
#pragma unroll
  for (int off = 32; off; off >>= 1) m = fmaxf(m, __shfl_xor(m, off));
  float e0 = expf(v0 - m), e1 = expf(v1 - m);
  float ssum = e0 + e1;
#pragma unroll
  for (int off = 32; off; off >>= 1) ssum += __shfl_xor(ssum, off);
  float inv = 1.f / ssum;
  e0 *= inv; e1 *= inv;
  r[lane] = e0; r[lane + 64] = e1;
  if ((row >> 6) == 62) {
    int b = row & 63;
    attnOut[b * 128 + lane] = e0;
    attnOut[b * 128 + lane + 64] = e1;
  }
}

__global__ __launch_bounds__(256) void attn_ctx(const float* __restrict__ attn,
                                                const float* __restrict__ srcEmb,
                                                float* __restrict__ out) {
  __shared__ float Wt[8][128];
  const int b = blockIdx.x;
  const int t0 = blockIdx.y << 3;
  const int nt = (TD - t0 < 8) ? (TD - t0) : 8;
  for (int i = threadIdx.x; i < nt * 128; i += 256) {
    int tl = i >> 7, s = i & 127;
    Wt[tl][s] = attn[((size_t)(t0 + tl) * BB + b) * 128 + s];
  }
  __syncthreads();
  const int e = threadIdx.x << 1;
  float acc[8][2] = {};
  for (int s = 0; s < 128; ++s) {
    float2 v = *reinterpret_cast<const float2*>(srcEmb + ((size_t)s * BB + b) * EE + e);
#pragma unroll
    for (int tl = 0; tl < 8; ++tl) {
      acc[tl][0] = fmaf(Wt[tl][s], v.x, acc[tl][0]);
      acc[tl][1] = fmaf(Wt[tl][s], v.y, acc[tl][1]);
    }
  }
  for (int tl = 0; tl < nt; ++tl) {
    float2 o = {acc[tl][0], acc[tl][1]};
    *reinterpret_cast<float2*>(out + ((size_t)b * 64 + (t0 + tl + 1)) * EE + e) = o;
  }
}

// ---------------- host ----------------

extern "C" void kernel_launch(void* const* d_in, const int* in_sizes, int n_in,
                              void* d_out, int out_size, void* d_ws, size_t ws_size,
                              hipStream_t stream) {
  const int* src = (const int*)d_in[0];
  const int* trg = (const int*)d_in[1];
  const float* srcTab = (const float*)d_in[2];
  const float* trgTab = (const float*)d_in[3];
  const float* fcW = (const float*)d_in[4];
  const float* fcB = (const float*)d_in[5];
  const float* Wih[4] = {(const float*)d_in[6], (const float*)d_in[10], (const float*)d_in[14], (const float*)d_in[18]};
  const float* Whh[4] = {(const float*)d_in[7], (const float*)d_in[11], (const float*)d_in[15], (const float*)d_in[19]};
  const float* bih[4] = {(const float*)d_in[8], (const float*)d_in[12], (const float*)d_in[16], (const float*)d_in[20]};
  const float* bhh[4] = {(const float*)d_in[9], (const float*)d_in[13], (const float*)d_in[17], (const float*)d_in[21]};

  // ws layout (floats), ~85 MB total:
  float* ws = (float*)d_ws;
  float* srcEmb  = ws;                   // [128][64][512]      4,194,304
  float* bufA    = srcEmb + 4194304;     //                      8,388,608
  float* decEmb  = bufA + 8388608;       // [64 pad][64][512]   2,097,152
  float* Gpre    = decEmb + 2097152;     // [16][64][4096]      4,194,304
  float* partial = Gpre + 4194304;       // [8][64][4096]       2,097,152
  float* hS      = partial + 2097152;    // [2][64][1024]         131,072
  float* cS      = hS + 131072;          //                       131,072

  float* encL0  = bufA;                  // [128][64][1024]
  float* decL0  = bufA;                  // [64 pad][64][1024]
  float* decOut = bufA + 4194304;        // [64 pad][64][1024]
  float* preds  = Gpre;                  // [64 pad * 64][512]
  float* scores = partial;               // [63][64][128]
  float* out = (float*)d_out;

  embed_src<<<SS * BB, 128, 0, stream>>>(src, srcTab, srcEmb);
  embed_dec<<<TD * BB, 128, 0, stream>>>(trg, trgTab, decEmb);
  zero_kernel<<<262144 / 256, 256, 0, stream>>>(hS, 262144);

  auto run_layer = [&](const float* inSeq, int T, int Din, int li,
                       float* hSt, float* cSt, float* outSeq) {
    for (int t0 = 0; t0 < T; t0 += 16) {
      int ct = (T - t0 < 16) ? (T - t0) : 16;
      // Gpre[16 steps][64][4096] = x @ Wih^T + bih + bhh  (M=1024 fixed; pad rows benign)
      gemm_proj_mfma<<<dim3(8, 32), 256, 0, stream>>>(
          inSeq + (size_t)t0 * BB * Din, Wih[li], bih[li], bhh[li], Gpre, G4, Din);
      for (int tc = 0; tc < ct; ++tc) {
        gemm_rec_mfma<<<256, 256, 0, stream>>>(hSt, Whh[li], partial);
        lstm_point<<<256, 256, 0, stream>>>(
            Gpre + (size_t)tc * BB * G4, partial, hSt, cSt,
            outSeq ? outSeq + (size_t)(t0 + tc) * BB * HH : (float*)nullptr);
      }
    }
  };

  run_layer(srcEmb, SS, EE, 0, hS, cS, encL0);
  run_layer(encL0, SS, HH, 1, hS + 65536, cS + 65536, nullptr);
  run_layer(decEmb, TD, EE, 2, hS, cS, decL0);
  run_layer(decL0, TD, HH, 3, hS + 65536, cS + 65536, decOut);

  // preds[4096 pad, 512] = decOut @ fcW^T + fcB
  gemm_proj_mfma<<<dim3(32, 4), 256, 0, stream>>>(decOut, fcW, fcB, nullptr, preds, 512, 1024);
  attn_scores<<<dim3(64, 8), 256, 0, stream>>>(preds, srcEmb, scores);
  softmax_attn<<<1008, 256, 0, stream>>>(scores, out + 2097152);
  attn_ctx<<<dim3(64, 8), 256, 0, stream>>>(scores, srcEmb, out);
  zero_row0<<<64, 512, 0, stream>>>(out);
}